// Round 5
// baseline (164.071 us; speedup 1.0000x reference)
//
#include <hip/hip_runtime.h>

#define NN 2048
#define DD 64
#define C1 0.36067376f  // 2/sqrt(D) * log2(e)
#define C1H 0.18033688f // C1/2
#define DEFER_THR 8.0f  // defer-max threshold: p <= 2^8, safe in f16

typedef _Float16 h8 __attribute__((ext_vector_type(8)));
typedef _Float16 h4 __attribute__((ext_vector_type(4)));
typedef float f32x16 __attribute__((ext_vector_type(16)));

union H8U4 { h8 v; unsigned u[4]; };

// ---- prep: frag-major swizzles so the main loop is pure coalesced loads ----
// Ks[bh][jj][c][lh][ln]{8}  = K[32jj+ln][16c+8lh+0..7]          (A-frag order)
// Vs[bh][jj][o][c][lh][ln]{8}= V[32jj+16c+8lh+j][32o+ln]        (V^T A-frag order)
// hk[bh][n] = C1H*||k_n||^2
__global__ __launch_bounds__(64) void prep(const float* __restrict__ k,
                                           const float* __restrict__ v,
                                           _Float16* __restrict__ Ks,
                                           _Float16* __restrict__ Vs,
                                           float* __restrict__ hk) {
    __shared__ _Float16 T[32][72];
    const int jj = blockIdx.x, bh = blockIdx.y, lane = threadIdx.x;
    const int ln = lane & 31, lh = lane >> 5;
    const size_t ibase = (size_t)bh * NN * DD + (size_t)jj * 32 * DD;

    { // K frags + row sumsq (lh halves cover complementary d-ranges)
        const float* kr = k + ibase + (size_t)ln * DD;
        float s = 0.f;
#pragma unroll
        for (int c = 0; c < 4; ++c) {
            float4 a = *(const float4*)&kr[16 * c + 8 * lh];
            float4 b = *(const float4*)&kr[16 * c + 8 * lh + 4];
            h8 o = {(_Float16)a.x, (_Float16)a.y, (_Float16)a.z, (_Float16)a.w,
                    (_Float16)b.x, (_Float16)b.y, (_Float16)b.z, (_Float16)b.w};
            *(h8*)&Ks[((size_t)bh * 16384 + jj * 256 + c * 64 + lh * 32 + ln) * 8] = o;
            s += a.x*a.x + a.y*a.y + a.z*a.z + a.w*a.w
               + b.x*b.x + b.y*b.y + b.z*b.z + b.w*b.w;
        }
        s += __shfl_xor(s, 32);
        if (lh == 0) hk[bh * NN + jj * 32 + ln] = s * C1H;
    }

    // V tile -> LDS f16 -> transposed frag-major store
#pragma unroll
    for (int t = 0; t < 8; ++t) {
        int f = lane + 64 * t;            // 512 float4 groups = 32 rows x 16
        int row = f >> 4, c4 = (f & 15) * 4;
        float4 a = *(const float4*)&v[ibase + (size_t)row * DD + c4];
        h4 hv = {(_Float16)a.x, (_Float16)a.y, (_Float16)a.z, (_Float16)a.w};
        *(h4*)&T[row][c4] = hv;
    }
    __syncthreads();
#pragma unroll
    for (int oc = 0; oc < 4; ++oc) {
        int o = oc >> 1, c = oc & 1;
        h8 r;
#pragma unroll
        for (int jx = 0; jx < 8; ++jx) r[jx] = T[16 * c + 8 * lh + jx][32 * o + ln];
        *(h8*)&Vs[((size_t)bh * 16384 + jj * 256 + o * 128 + c * 64 + lh * 32 + ln) * 8] = r;
    }
}

// ---- main: flash RBF, defer-max softmax, key-split across 2 waves per q-tile ----
// Block = 2 waves on the SAME 32-row q-tile; wave0 keys [0,ceil(T/2)), wave1 the
// rest incl. diagonal. Partials (m,l,O) flash-merge through LDS.
// Register budget engineered for 3 waves/SIMD (~170-reg class): kf double-buffered,
// vf/hk single-buffered (latency hidden under QK MFMAs). R3 lesson: a LARGE
// shortfall vs the launch_bounds cap causes total scratch spill — watch WRITE_SIZE.
__global__ __launch_bounds__(128, 3) void rbf_attn(
    const float* __restrict__ q, const _Float16* __restrict__ Ks,
    const _Float16* __restrict__ Vs, const float* __restrict__ hk,
    float* __restrict__ out)
{
    __shared__ float sm[64][34];         // wave1: O (32 f32/lane) + l + m
    const int tid = threadIdx.x;
    const int bh = blockIdx.x;
    const int qt = 63 - (int)blockIdx.y; // q-tile (32 rows); LPT: heavy first
    const int wv = tid >> 6, lane = tid & 63;
    const int ln = lane & 31, lh = lane >> 5;
    const int qrow = qt * 32 + ln;
    const size_t fbase = (size_t)bh * NN * DD;

    // Q B-frags straight from global f32 (per-lane 16B-contiguous, L1/L2-hot)
    h8 qf[4];
    {
        const float* qr = q + fbase + (size_t)qrow * DD;
#pragma unroll
        for (int c = 0; c < 4; ++c) {
            float4 a = *(const float4*)&qr[16 * c + 8 * lh];
            float4 b = *(const float4*)&qr[16 * c + 8 * lh + 4];
            qf[c] = h8{(_Float16)a.x, (_Float16)a.y, (_Float16)a.z, (_Float16)a.w,
                       (_Float16)b.x, (_Float16)b.y, (_Float16)b.z, (_Float16)b.w};
        }
    }

    const _Float16* Ksb = Ks + (size_t)bh * 131072;
    const _Float16* Vsb = Vs + (size_t)bh * 131072;
    const float4* hk4 = (const float4*)(hk + bh * NN);
    const int klq = (lh * 32 + ln) * 8;  // element offset of this lane's frag

    f32x16 O0, O1;
#pragma unroll
    for (int r = 0; r < 16; ++r) { O0[r] = 0.f; O1[r] = 0.f; }
    float lsum = 0.f, mrun = -INFINITY;

    const int T = qt + 1;                // key tiles for this q-tile
    const int half = (T + 1) >> 1;       // wave0 gets ceil (wave1 pays diag mask)
    const int j0 = wv ? half : 0;
    const int j1 = wv ? T : half;

    auto loadK = [&](int jj, h8 (&kf)[4]) {
        const _Float16* kp = Ksb + (size_t)jj * 2048 + klq;
#pragma unroll
        for (int c = 0; c < 4; ++c) kf[c] = *(const h8*)(kp + c * 512);
    };

    auto comp = [&](int jj, h8 (&kf)[4]) {
        // current-tile hk + V loads (single-buffered; hidden under QK + softmax)
        float4 hr[4];
#pragma unroll
        for (int g = 0; g < 4; ++g) hr[g] = hk4[jj * 8 + g * 2 + lh];
        h8 vf[4];
        const _Float16* vp = Vsb + (size_t)jj * 2048 + klq;
#pragma unroll
        for (int oc = 0; oc < 4; ++oc)
            vf[oc] = *(const h8*)(vp + (oc >> 1) * 1024 + (oc & 1) * 512);

        f32x16 S;
#pragma unroll
        for (int r = 0; r < 16; ++r) S[r] = 0.f;
        __builtin_amdgcn_s_setprio(1);
#pragma unroll
        for (int c = 0; c < 4; ++c)
            S = __builtin_amdgcn_mfma_f32_32x32x16_f16(kf[c], qf[c], S, 0, 0, 0);
        __builtin_amdgcn_s_setprio(0);

        const bool diag = (jj == qt);    // only the diagonal-owning wave hits this
        float t[16];
#pragma unroll
        for (int r = 0; r < 16; ++r) {
            const float* hf = (const float*)&hr[r >> 2];
            float tv = fmaf(S[r], C1, -(hf[r & 3] + mrun));  // x - mrun
            if (diag) {
                int keyloc = (r & 3) + 8 * (r >> 2) + 4 * lh;
                if (keyloc > ln) tv = -INFINITY;
            }
            t[r] = tv;
        }
        // tree max of shifted logits (defer guard)
        float a0 = fmaxf(t[0], t[1]),  a1 = fmaxf(t[2], t[3]);
        float a2 = fmaxf(t[4], t[5]),  a3 = fmaxf(t[6], t[7]);
        float a4 = fmaxf(t[8], t[9]),  a5 = fmaxf(t[10], t[11]);
        float a6 = fmaxf(t[12], t[13]), a7 = fmaxf(t[14], t[15]);
        float fm = fmaxf(fmaxf(fmaxf(a0, a1), fmaxf(a2, a3)),
                         fmaxf(fmaxf(a4, a5), fmaxf(a6, a7)));

        if (__any(fm > DEFER_THR)) {
            // slow path (first tile + rare record tiles): exact logits in place
#pragma unroll
            for (int r = 0; r < 16; ++r) {
                const float* hf = (const float*)&hr[r >> 2];
                float xv = fmaf(S[r], C1, -hf[r & 3]);
                if (diag) {
                    int keyloc = (r & 3) + 8 * (r >> 2) + 4 * lh;
                    if (keyloc > ln) xv = -INFINITY;
                }
                S[r] = xv;
            }
            float c0 = fmaxf(fmaxf(S[0], S[1]), fmaxf(S[2], S[3]));
            float c1 = fmaxf(fmaxf(S[4], S[5]), fmaxf(S[6], S[7]));
            float c2 = fmaxf(fmaxf(S[8], S[9]), fmaxf(S[10], S[11]));
            float c3 = fmaxf(fmaxf(S[12], S[13]), fmaxf(S[14], S[15]));
            float mtl = fmaxf(fmaxf(c0, c1), fmaxf(c2, c3));
            float mt = fmaxf(mtl, __shfl_xor(mtl, 32));
            float mnew = fmaxf(mrun, mt);
            float alpha = __builtin_amdgcn_exp2f(mrun - mnew);  // -inf -> 0 ok
#pragma unroll
            for (int r = 0; r < 16; ++r) t[r] = S[r] - mnew;
            lsum *= alpha;
#pragma unroll
            for (int r = 0; r < 16; ++r) { O0[r] *= alpha; O1[r] *= alpha; }
            mrun = mnew;
        }
        // shared epilogue: p = exp2(t), sum, pack, PV
#pragma unroll
        for (int r = 0; r < 16; ++r) t[r] = __builtin_amdgcn_exp2f(t[r]);
        float ps = (((t[0] + t[1]) + (t[2] + t[3])) + ((t[4] + t[5]) + (t[6] + t[7])))
                 + (((t[8] + t[9]) + (t[10] + t[11])) + ((t[12] + t[13]) + (t[14] + t[15])));
        lsum += ps;

        unsigned pk[8];
#pragma unroll
        for (int hh = 0; hh < 8; ++hh) {
            auto pr = __builtin_amdgcn_cvt_pkrtz(t[2 * hh], t[2 * hh + 1]);
            unsigned pu; __builtin_memcpy(&pu, &pr, 4);
            pk[hh] = pu;
        }
        __builtin_amdgcn_s_setprio(1);
#pragma unroll
        for (int s = 0; s < 2; ++s) {       // C-frag -> B-frag(P^T): lane^32 swap
            unsigned send0 = lh ? pk[4 * s + 0] : pk[4 * s + 2];
            unsigned send1 = lh ? pk[4 * s + 1] : pk[4 * s + 3];
            unsigned r0 = (unsigned)__shfl_xor((int)send0, 32);
            unsigned r1 = (unsigned)__shfl_xor((int)send1, 32);
            H8U4 pb;
            pb.u[0] = lh ? r0 : pk[4 * s + 0];
            pb.u[1] = lh ? r1 : pk[4 * s + 1];
            pb.u[2] = lh ? pk[4 * s + 2] : r0;
            pb.u[3] = lh ? pk[4 * s + 3] : r1;
            O0 = __builtin_amdgcn_mfma_f32_32x32x16_f16(vf[s], pb.v, O0, 0, 0, 0);
            O1 = __builtin_amdgcn_mfma_f32_32x32x16_f16(vf[2 + s], pb.v, O1, 0, 0, 0);
        }
        __builtin_amdgcn_s_setprio(0);
    };

    // rotated 2-deep K pipeline (no dynamic reg indexing)
    h8 kfA[4], kfB[4];
    if (j0 < j1) {
        loadK(j0, kfA);
        int jj = j0;
        while (true) {
            if (jj + 1 < j1) loadK(jj + 1, kfB);
            comp(jj, kfA);
            if (++jj >= j1) break;
            if (jj + 1 < j1) loadK(jj + 1, kfA);
            comp(jj, kfB);
            if (++jj >= j1) break;
        }
    }

    // merge: wave1 publishes (m,l,O); wave0 flash-combines, normalizes, stores
    if (wv) {
#pragma unroll
        for (int r = 0; r < 16; ++r) { sm[lane][r] = O0[r]; sm[lane][16 + r] = O1[r]; }
        sm[lane][32] = lsum + __shfl_xor(lsum, 32);
        sm[lane][33] = mrun;
    }
    __syncthreads();
    if (!wv) {
        float l0 = lsum + __shfl_xor(lsum, 32);
        float l1 = sm[lane][32];
        float m1 = sm[lane][33];
        float m = fmaxf(mrun, m1);
        float a0 = __builtin_amdgcn_exp2f(mrun - m);
        float a1 = __builtin_amdgcn_exp2f(m1 - m);   // wave1 empty: m1=-inf -> 0
        float lt = l0 * a0 + l1 * a1;
        float inv = 1.f / lt;
        float s0 = a0 * inv, s1 = a1 * inv;
        size_t ro = fbase + (size_t)qrow * DD;
#pragma unroll
        for (int g = 0; g < 4; ++g) {
            float4 o0 = make_float4(O0[4 * g + 0] * s0 + sm[lane][4 * g + 0] * s1,
                                    O0[4 * g + 1] * s0 + sm[lane][4 * g + 1] * s1,
                                    O0[4 * g + 2] * s0 + sm[lane][4 * g + 2] * s1,
                                    O0[4 * g + 3] * s0 + sm[lane][4 * g + 3] * s1);
            *(float4*)&out[ro + 8 * g + 4 * lh] = o0;
            float4 o1 = make_float4(O1[4 * g + 0] * s0 + sm[lane][16 + 4 * g + 0] * s1,
                                    O1[4 * g + 1] * s0 + sm[lane][16 + 4 * g + 1] * s1,
                                    O1[4 * g + 2] * s0 + sm[lane][16 + 4 * g + 2] * s1,
                                    O1[4 * g + 3] * s0 + sm[lane][16 + 4 * g + 3] * s1);
            *(float4*)&out[ro + 32 + 8 * g + 4 * lh] = o1;
        }
    }
}

extern "C" void kernel_launch(void* const* d_in, const int* in_sizes, int n_in,
                              void* d_out, int out_size, void* d_ws, size_t ws_size,
                              hipStream_t stream) {
    (void)in_sizes; (void)n_in; (void)out_size; (void)ws_size;
    const float* q = (const float*)d_in[0];
    const float* k = (const float*)d_in[1];
    const float* v = (const float*)d_in[2];
    float* out = (float*)d_out;

    // ws: [hk 256KB][Ks 8MB f16][Vs 8MB f16]
    float* hk = (float*)d_ws;
    _Float16* Ks = (_Float16*)((char*)d_ws + 262144);
    _Float16* Vs = (_Float16*)((char*)d_ws + 262144 + 8388608);

    prep<<<dim3(64, 32), 64, 0, stream>>>(k, v, Ks, Vs, hk);
    rbf_attn<<<dim3(32, 64), 128, 0, stream>>>(q, Ks, Vs, hk, out);
}

// Round 6
// 133.763 us; speedup vs baseline: 1.2266x; 1.2266x over previous
//
#include <hip/hip_runtime.h>

#define NN 2048
#define DD 64
#define C1 0.36067376f  // 2/sqrt(D) * log2(e)
#define C1H 0.18033688f // C1/2
#define DEFER_THR 8.0f  // defer-max threshold: p <= 2^8, safe in f16

typedef _Float16 h8 __attribute__((ext_vector_type(8)));
typedef _Float16 h4 __attribute__((ext_vector_type(4)));
typedef float f32x16 __attribute__((ext_vector_type(16)));

union H8U4 { h8 v; unsigned u[4]; };

// ---- prep: frag-major swizzles so the main loop is pure coalesced loads ----
// Ks[bh][jj][c][lh][ln]{8}  = K[32jj+ln][16c+8lh+0..7]          (A-frag order)
// Vs[bh][jj][o][c][lh][ln]{8}= V[32jj+16c+8lh+j][32o+ln]        (V^T A-frag order)
// hk[bh][n] = C1H*||k_n||^2
__global__ __launch_bounds__(64) void prep(const float* __restrict__ k,
                                           const float* __restrict__ v,
                                           _Float16* __restrict__ Ks,
                                           _Float16* __restrict__ Vs,
                                           float* __restrict__ hk) {
    __shared__ _Float16 T[32][72];
    const int jj = blockIdx.x, bh = blockIdx.y, lane = threadIdx.x;
    const int ln = lane & 31, lh = lane >> 5;
    const size_t ibase = (size_t)bh * NN * DD + (size_t)jj * 32 * DD;

    { // K frags + row sumsq (lh halves cover complementary d-ranges)
        const float* kr = k + ibase + (size_t)ln * DD;
        float s = 0.f;
#pragma unroll
        for (int c = 0; c < 4; ++c) {
            float4 a = *(const float4*)&kr[16 * c + 8 * lh];
            float4 b = *(const float4*)&kr[16 * c + 8 * lh + 4];
            h8 o = {(_Float16)a.x, (_Float16)a.y, (_Float16)a.z, (_Float16)a.w,
                    (_Float16)b.x, (_Float16)b.y, (_Float16)b.z, (_Float16)b.w};
            *(h8*)&Ks[((size_t)bh * 16384 + jj * 256 + c * 64 + lh * 32 + ln) * 8] = o;
            s += a.x*a.x + a.y*a.y + a.z*a.z + a.w*a.w
               + b.x*b.x + b.y*b.y + b.z*b.z + b.w*b.w;
        }
        s += __shfl_xor(s, 32);
        if (lh == 0) hk[bh * NN + jj * 32 + ln] = s * C1H;
    }

    // V tile -> LDS f16 -> transposed frag-major store
#pragma unroll
    for (int t = 0; t < 8; ++t) {
        int f = lane + 64 * t;            // 512 float4 groups = 32 rows x 16
        int row = f >> 4, c4 = (f & 15) * 4;
        float4 a = *(const float4*)&v[ibase + (size_t)row * DD + c4];
        h4 hv = {(_Float16)a.x, (_Float16)a.y, (_Float16)a.z, (_Float16)a.w};
        *(h4*)&T[row][c4] = hv;
    }
    __syncthreads();
#pragma unroll
    for (int oc = 0; oc < 4; ++oc) {
        int o = oc >> 1, c = oc & 1;
        h8 r;
#pragma unroll
        for (int jx = 0; jx < 8; ++jx) r[jx] = T[16 * c + 8 * lh + jx][32 * o + ln];
        *(h8*)&Vs[((size_t)bh * 16384 + jj * 256 + o * 128 + c * 64 + lh * 32 + ln) * 8] = r;
    }
}

// ---- main: flash RBF, defer-max softmax, key-split across 2 waves per q-tile ----
// Block = 2 waves on the SAME 32-row q-tile; wave0 keys [0,ceil(T/2)), wave1 the
// rest incl. diagonal. Partials (m,l,O) flash-merge through LDS.
// REGISTER CLASS IS FIXED: ~184 unified regs -> 2 waves/SIMD. Forcing 3 (R5) or
// 4 (R3) waves/SIMD spills to scratch (WRITE_SIZE 94MB/756MB). Keep (128, 2).
__global__ __launch_bounds__(128, 2) void rbf_attn(
    const float* __restrict__ q, const _Float16* __restrict__ Ks,
    const _Float16* __restrict__ Vs, const float* __restrict__ hk,
    float* __restrict__ out)
{
    __shared__ float sm[64][34];         // wave1: O (32 f32/lane) + l + m
    const int tid = threadIdx.x;
    const int bh = blockIdx.x;
    const int qt = 63 - (int)blockIdx.y; // q-tile (32 rows); LPT: heavy first
    const int wv = tid >> 6, lane = tid & 63;
    const int ln = lane & 31, lh = lane >> 5;
    const int qrow = qt * 32 + ln;
    const size_t fbase = (size_t)bh * NN * DD;

    // Q B-frags straight from global f32 (per-lane 16B-contiguous, L1/L2-hot)
    h8 qf[4];
    {
        const float* qr = q + fbase + (size_t)qrow * DD;
#pragma unroll
        for (int c = 0; c < 4; ++c) {
            float4 a = *(const float4*)&qr[16 * c + 8 * lh];
            float4 b = *(const float4*)&qr[16 * c + 8 * lh + 4];
            qf[c] = h8{(_Float16)a.x, (_Float16)a.y, (_Float16)a.z, (_Float16)a.w,
                       (_Float16)b.x, (_Float16)b.y, (_Float16)b.z, (_Float16)b.w};
        }
    }

    const _Float16* Ksb = Ks + (size_t)bh * 131072;
    const _Float16* Vsb = Vs + (size_t)bh * 131072;
    const float4* hk4 = (const float4*)(hk + bh * NN);
    const int klq = (lh * 32 + ln) * 8;  // element offset of this lane's frag

    f32x16 O0, O1;
#pragma unroll
    for (int r = 0; r < 16; ++r) { O0[r] = 0.f; O1[r] = 0.f; }
    float lsum = 0.f, mrun = -INFINITY;

    const int T = qt + 1;                // key tiles for this q-tile
    const int half = (T + 1) >> 1;       // wave0 gets ceil (wave1 pays diag mask)
    const int j0 = wv ? half : 0;
    const int j1 = wv ? T : half;

    auto loadT = [&](int jj, h8 (&kf)[4], h8 (&vf)[4], float4 (&hr)[4]) {
        const _Float16* kp = Ksb + (size_t)jj * 2048 + klq;
        const _Float16* vp = Vsb + (size_t)jj * 2048 + klq;
#pragma unroll
        for (int c = 0; c < 4; ++c) kf[c] = *(const h8*)(kp + c * 512);
#pragma unroll
        for (int oc = 0; oc < 4; ++oc)
            vf[oc] = *(const h8*)(vp + (oc >> 1) * 1024 + (oc & 1) * 512);
#pragma unroll
        for (int g = 0; g < 4; ++g) hr[g] = hk4[jj * 8 + g * 2 + lh];
    };

    auto comp = [&](int jj, h8 (&kf)[4], h8 (&vf)[4], float4 (&hr)[4]) {
        f32x16 S;
#pragma unroll
        for (int r = 0; r < 16; ++r) S[r] = 0.f;
        __builtin_amdgcn_s_setprio(1);
#pragma unroll
        for (int c = 0; c < 4; ++c)
            S = __builtin_amdgcn_mfma_f32_32x32x16_f16(kf[c], qf[c], S, 0, 0, 0);
        __builtin_amdgcn_s_setprio(0);

        const bool diag = (jj == qt);    // only the diagonal-owning wave hits this
        float t[16];
#pragma unroll
        for (int r = 0; r < 16; ++r) {
            const float* hf = (const float*)&hr[r >> 2];
            float tv = fmaf(S[r], C1, -(hf[r & 3] + mrun));  // x - mrun
            if (diag) {
                int keyloc = (r & 3) + 8 * (r >> 2) + 4 * lh;
                if (keyloc > ln) tv = -INFINITY;
            }
            t[r] = tv;
        }
        // tree max of shifted logits (defer guard only)
        float a0 = fmaxf(t[0], t[1]),  a1 = fmaxf(t[2], t[3]);
        float a2 = fmaxf(t[4], t[5]),  a3 = fmaxf(t[6], t[7]);
        float a4 = fmaxf(t[8], t[9]),  a5 = fmaxf(t[10], t[11]);
        float a6 = fmaxf(t[12], t[13]), a7 = fmaxf(t[14], t[15]);
        float fm = fmaxf(fmaxf(fmaxf(a0, a1), fmaxf(a2, a3)),
                         fmaxf(fmaxf(a4, a5), fmaxf(a6, a7)));

        if (__any(fm > DEFER_THR)) {
            // slow path (first tile + rare record tiles): exact logits in place
#pragma unroll
            for (int r = 0; r < 16; ++r) {
                const float* hf = (const float*)&hr[r >> 2];
                float xv = fmaf(S[r], C1, -hf[r & 3]);
                if (diag) {
                    int keyloc = (r & 3) + 8 * (r >> 2) + 4 * lh;
                    if (keyloc > ln) xv = -INFINITY;
                }
                S[r] = xv;
            }
            float c0 = fmaxf(fmaxf(S[0], S[1]), fmaxf(S[2], S[3]));
            float c1 = fmaxf(fmaxf(S[4], S[5]), fmaxf(S[6], S[7]));
            float c2 = fmaxf(fmaxf(S[8], S[9]), fmaxf(S[10], S[11]));
            float c3 = fmaxf(fmaxf(S[12], S[13]), fmaxf(S[14], S[15]));
            float mtl = fmaxf(fmaxf(c0, c1), fmaxf(c2, c3));
            float mt = fmaxf(mtl, __shfl_xor(mtl, 32));
            float mnew = fmaxf(mrun, mt);
            float alpha = __builtin_amdgcn_exp2f(mrun - mnew);  // -inf -> 0 ok
#pragma unroll
            for (int r = 0; r < 16; ++r) t[r] = S[r] - mnew;
            lsum *= alpha;
#pragma unroll
            for (int r = 0; r < 16; ++r) { O0[r] *= alpha; O1[r] *= alpha; }
            mrun = mnew;
        }
        // shared epilogue: p = exp2(t), sum, pack, PV
#pragma unroll
        for (int r = 0; r < 16; ++r) t[r] = __builtin_amdgcn_exp2f(t[r]);
        float ps = (((t[0] + t[1]) + (t[2] + t[3])) + ((t[4] + t[5]) + (t[6] + t[7])))
                 + (((t[8] + t[9]) + (t[10] + t[11])) + ((t[12] + t[13]) + (t[14] + t[15])));
        lsum += ps;

        unsigned pk[8];
#pragma unroll
        for (int hh = 0; hh < 8; ++hh) {
            auto pr = __builtin_amdgcn_cvt_pkrtz(t[2 * hh], t[2 * hh + 1]);
            unsigned pu; __builtin_memcpy(&pu, &pr, 4);
            pk[hh] = pu;
        }
        __builtin_amdgcn_s_setprio(1);
#pragma unroll
        for (int s = 0; s < 2; ++s) {       // C-frag -> B-frag(P^T): lane^32 swap
            unsigned send0 = lh ? pk[4 * s + 0] : pk[4 * s + 2];
            unsigned send1 = lh ? pk[4 * s + 1] : pk[4 * s + 3];
            unsigned r0 = (unsigned)__shfl_xor((int)send0, 32);
            unsigned r1 = (unsigned)__shfl_xor((int)send1, 32);
            H8U4 pb;
            pb.u[0] = lh ? r0 : pk[4 * s + 0];
            pb.u[1] = lh ? r1 : pk[4 * s + 1];
            pb.u[2] = lh ? pk[4 * s + 2] : r0;
            pb.u[3] = lh ? pk[4 * s + 3] : r1;
            O0 = __builtin_amdgcn_mfma_f32_32x32x16_f16(vf[s], pb.v, O0, 0, 0, 0);
            O1 = __builtin_amdgcn_mfma_f32_32x32x16_f16(vf[2 + s], pb.v, O1, 0, 0, 0);
        }
        __builtin_amdgcn_s_setprio(0);
    };

    // rotated 2-deep register pipeline (no dynamic reg indexing)
    h8 kfA[4], vfA[4]; float4 hrA[4];
    h8 kfB[4], vfB[4]; float4 hrB[4];
    if (j0 < j1) {
        loadT(j0, kfA, vfA, hrA);
        int jj = j0;
        while (true) {
            if (jj + 1 < j1) loadT(jj + 1, kfB, vfB, hrB);
            comp(jj, kfA, vfA, hrA);
            if (++jj >= j1) break;
            if (jj + 1 < j1) loadT(jj + 1, kfA, vfA, hrA);
            comp(jj, kfB, vfB, hrB);
            if (++jj >= j1) break;
        }
    }

    // merge: wave1 publishes (m,l,O); wave0 flash-combines, normalizes, stores
    if (wv) {
#pragma unroll
        for (int r = 0; r < 16; ++r) { sm[lane][r] = O0[r]; sm[lane][16 + r] = O1[r]; }
        sm[lane][32] = lsum + __shfl_xor(lsum, 32);
        sm[lane][33] = mrun;
    }
    __syncthreads();
    if (!wv) {
        float l0 = lsum + __shfl_xor(lsum, 32);
        float l1 = sm[lane][32];
        float m1 = sm[lane][33];
        float m = fmaxf(mrun, m1);
        float a0 = __builtin_amdgcn_exp2f(mrun - m);
        float a1 = __builtin_amdgcn_exp2f(m1 - m);   // wave1 empty: m1=-inf -> 0
        float lt = l0 * a0 + l1 * a1;
        float inv = 1.f / lt;
        float s0 = a0 * inv, s1 = a1 * inv;
        size_t ro = fbase + (size_t)qrow * DD;
#pragma unroll
        for (int g = 0; g < 4; ++g) {
            float4 o0 = make_float4(O0[4 * g + 0] * s0 + sm[lane][4 * g + 0] * s1,
                                    O0[4 * g + 1] * s0 + sm[lane][4 * g + 1] * s1,
                                    O0[4 * g + 2] * s0 + sm[lane][4 * g + 2] * s1,
                                    O0[4 * g + 3] * s0 + sm[lane][4 * g + 3] * s1);
            *(float4*)&out[ro + 8 * g + 4 * lh] = o0;
            float4 o1 = make_float4(O1[4 * g + 0] * s0 + sm[lane][16 + 4 * g + 0] * s1,
                                    O1[4 * g + 1] * s0 + sm[lane][16 + 4 * g + 1] * s1,
                                    O1[4 * g + 2] * s0 + sm[lane][16 + 4 * g + 2] * s1,
                                    O1[4 * g + 3] * s0 + sm[lane][16 + 4 * g + 3] * s1);
            *(float4*)&out[ro + 32 + 8 * g + 4 * lh] = o1;
        }
    }
}

extern "C" void kernel_launch(void* const* d_in, const int* in_sizes, int n_in,
                              void* d_out, int out_size, void* d_ws, size_t ws_size,
                              hipStream_t stream) {
    (void)in_sizes; (void)n_in; (void)out_size; (void)ws_size;
    const float* q = (const float*)d_in[0];
    const float* k = (const float*)d_in[1];
    const float* v = (const float*)d_in[2];
    float* out = (float*)d_out;

    // ws: [hk 256KB][Ks 8MB f16][Vs 8MB f16]
    float* hk = (float*)d_ws;
    _Float16* Ks = (_Float16*)((char*)d_ws + 262144);
    _Float16* Vs = (_Float16*)((char*)d_ws + 262144 + 8388608);

    prep<<<dim3(64, 32), 64, 0, stream>>>(k, v, Ks, Vs, hk);
    rbf_attn<<<dim3(32, 64), 128, 0, stream>>>(q, Ks, Vs, hk, out);
}

// Round 7
// 129.577 us; speedup vs baseline: 1.2662x; 1.0323x over previous
//
#include <hip/hip_runtime.h>

#define NN 2048
#define DD 64
#define C1 0.36067376f  // 2/sqrt(D) * log2(e)
#define C1H 0.18033688f // C1/2

typedef _Float16 h8 __attribute__((ext_vector_type(8)));
typedef _Float16 h4 __attribute__((ext_vector_type(4)));
typedef float f32x16 __attribute__((ext_vector_type(16)));

union H8U4 { h8 v; unsigned u[4]; };

// ---- prep: frag-major swizzles so the main loop is pure coalesced loads ----
// Ks[bh][jj][c][lh][ln]{8}  = K[32jj+ln][16c+8lh+0..7]          (A-frag order)
// Vs[bh][jj][o][c][lh][ln]{8}= V[32jj+16c+8lh+j][32o+ln]        (V^T A-frag order)
// hk[bh][n] = C1H*||k_n||^2
__global__ __launch_bounds__(64) void prep(const float* __restrict__ k,
                                           const float* __restrict__ v,
                                           _Float16* __restrict__ Ks,
                                           _Float16* __restrict__ Vs,
                                           float* __restrict__ hk) {
    __shared__ _Float16 T[32][72];
    const int jj = blockIdx.x, bh = blockIdx.y, lane = threadIdx.x;
    const int ln = lane & 31, lh = lane >> 5;
    const size_t ibase = (size_t)bh * NN * DD + (size_t)jj * 32 * DD;

    { // K frags + row sumsq (lh halves cover complementary d-ranges)
        const float* kr = k + ibase + (size_t)ln * DD;
        float s = 0.f;
#pragma unroll
        for (int c = 0; c < 4; ++c) {
            float4 a = *(const float4*)&kr[16 * c + 8 * lh];
            float4 b = *(const float4*)&kr[16 * c + 8 * lh + 4];
            h8 o = {(_Float16)a.x, (_Float16)a.y, (_Float16)a.z, (_Float16)a.w,
                    (_Float16)b.x, (_Float16)b.y, (_Float16)b.z, (_Float16)b.w};
            *(h8*)&Ks[((size_t)bh * 16384 + jj * 256 + c * 64 + lh * 32 + ln) * 8] = o;
            s += a.x*a.x + a.y*a.y + a.z*a.z + a.w*a.w
               + b.x*b.x + b.y*b.y + b.z*b.z + b.w*b.w;
        }
        s += __shfl_xor(s, 32);
        if (lh == 0) hk[bh * NN + jj * 32 + ln] = s * C1H;
    }

    // V tile -> LDS f16 -> transposed frag-major store
#pragma unroll
    for (int t = 0; t < 8; ++t) {
        int f = lane + 64 * t;            // 512 float4 groups = 32 rows x 16
        int row = f >> 4, c4 = (f & 15) * 4;
        float4 a = *(const float4*)&v[ibase + (size_t)row * DD + c4];
        h4 hv = {(_Float16)a.x, (_Float16)a.y, (_Float16)a.z, (_Float16)a.w};
        *(h4*)&T[row][c4] = hv;
    }
    __syncthreads();
#pragma unroll
    for (int oc = 0; oc < 4; ++oc) {
        int o = oc >> 1, c = oc & 1;
        h8 r;
#pragma unroll
        for (int jx = 0; jx < 8; ++jx) r[jx] = T[16 * c + 8 * lh + jx][32 * o + ln];
        *(h8*)&Vs[((size_t)bh * 16384 + jj * 256 + o * 128 + c * 64 + lh * 32 + ln) * 8] = r;
    }
}

// ---- main: flash RBF, paired complementary q-tiles + key-split-2 ----
// Block = 2 waves on the q-tile PAIR (qt1=p, qt2=63-p). Total work per pair is
// T1+T2 = 65 tile-units, constant -> 1024 uniform blocks, one generation, no
// drain tail. Each wave takes half of qt2's key range [0,T2); per loaded K/V
// tile it computes qt2 always and qt1 when jj<T1 (shared loads, -25% L2
// traffic; two independent dep chains -> 2x ILP in the latency-bound wave).
// REGISTER CLASS: ~230 unified regs -> 2 waves/SIMD (R3/R5: forcing more
// spills to scratch; sentinel = WRITE_SIZE 16.4 MB). kf double-buffered only;
// vf/hr loaded at comp top, consumed under QK+softmax.
__global__ __launch_bounds__(128, 2) void rbf_attn(
    const float* __restrict__ q, const _Float16* __restrict__ Ks,
    const _Float16* __restrict__ Vs, const float* __restrict__ hk,
    float* __restrict__ out)
{
    __shared__ float sm[2][64][34];      // wave1 publish: per q-tile O + l + m
    const int tid = threadIdx.x;
    const int bh = blockIdx.x;
    const int pr = blockIdx.y;           // pair index 0..31
    const int qt1 = pr, qt2 = 63 - pr;
    const int wv = tid >> 6, lane = tid & 63;
    const int ln = lane & 31, lh = lane >> 5;
    const size_t fbase = (size_t)bh * NN * DD;

    // Q B-frags for BOTH q-tiles straight from global f32
    h8 qf1[4], qf2[4];
    {
        const float* qr1 = q + fbase + (size_t)(qt1 * 32 + ln) * DD;
        const float* qr2 = q + fbase + (size_t)(qt2 * 32 + ln) * DD;
#pragma unroll
        for (int c = 0; c < 4; ++c) {
            float4 a = *(const float4*)&qr1[16 * c + 8 * lh];
            float4 b = *(const float4*)&qr1[16 * c + 8 * lh + 4];
            qf1[c] = h8{(_Float16)a.x, (_Float16)a.y, (_Float16)a.z, (_Float16)a.w,
                        (_Float16)b.x, (_Float16)b.y, (_Float16)b.z, (_Float16)b.w};
            float4 e = *(const float4*)&qr2[16 * c + 8 * lh];
            float4 f = *(const float4*)&qr2[16 * c + 8 * lh + 4];
            qf2[c] = h8{(_Float16)e.x, (_Float16)e.y, (_Float16)e.z, (_Float16)e.w,
                        (_Float16)f.x, (_Float16)f.y, (_Float16)f.z, (_Float16)f.w};
        }
    }

    const _Float16* Ksb = Ks + (size_t)bh * 131072;
    const _Float16* Vsb = Vs + (size_t)bh * 131072;
    const float4* hk4 = (const float4*)(hk + bh * NN);
    const int klq = (lh * 32 + ln) * 8;  // element offset of this lane's frag

    f32x16 O0a, O1a, O0b, O1b;
#pragma unroll
    for (int r = 0; r < 16; ++r) { O0a[r] = 0.f; O1a[r] = 0.f; O0b[r] = 0.f; O1b[r] = 0.f; }
    float l1 = 0.f, m1 = -INFINITY;      // qt1 online-softmax state
    float l2 = 0.f, m2 = -INFINITY;      // qt2 state

    const int T1 = qt1 + 1, T2 = qt2 + 1;
    const int h2 = (T2 + 1) >> 1;        // wave0: [0,h2), wave1: [h2,T2)
    const int j0 = wv ? h2 : 0;
    const int j1 = wv ? T2 : h2;

    auto loadK = [&](int jj, h8 (&kf)[4]) {
        const _Float16* kp = Ksb + (size_t)jj * 2048 + klq;
#pragma unroll
        for (int c = 0; c < 4; ++c) kf[c] = *(const h8*)(kp + c * 512);
    };

    // verified R2 comp body, parameterized by q-state
    auto compQ = [&](int jj, const h8 (&kf)[4], const h8 (&vf)[4],
                     const float4 (&hr)[4], const h8 (&qf)[4],
                     f32x16& O0, f32x16& O1, float& mrun, float& lsum, int dqt) {
        f32x16 S;
#pragma unroll
        for (int r = 0; r < 16; ++r) S[r] = 0.f;
#pragma unroll
        for (int c = 0; c < 4; ++c)
            S = __builtin_amdgcn_mfma_f32_32x32x16_f16(kf[c], qf[c], S, 0, 0, 0);

        const bool diag = (jj == dqt);
        float x[16];
#pragma unroll
        for (int r = 0; r < 16; ++r) {
            const float* hf = (const float*)&hr[r >> 2];
            float xv = fmaf(S[r], C1, -hf[r & 3]);
            if (diag) {
                int keyloc = (r & 3) + 8 * (r >> 2) + 4 * lh;
                if (keyloc > ln) xv = -INFINITY;
            }
            x[r] = xv;
        }
        // fmax tree (exact op, order-free)
        float a0 = fmaxf(x[0], x[1]),  a1 = fmaxf(x[2], x[3]);
        float a2 = fmaxf(x[4], x[5]),  a3 = fmaxf(x[6], x[7]);
        float a4 = fmaxf(x[8], x[9]),  a5 = fmaxf(x[10], x[11]);
        float a6 = fmaxf(x[12], x[13]), a7 = fmaxf(x[14], x[15]);
        float mt = fmaxf(fmaxf(fmaxf(a0, a1), fmaxf(a2, a3)),
                         fmaxf(fmaxf(a4, a5), fmaxf(a6, a7)));
        mt = fmaxf(mt, __shfl_xor(mt, 32));
        float mnew = fmaxf(mrun, mt);
        float alpha = __builtin_amdgcn_exp2f(mrun - mnew);
        mrun = mnew;
        float p[16], ps;
#pragma unroll
        for (int r = 0; r < 16; ++r) p[r] = __builtin_amdgcn_exp2f(x[r] - mnew);
        ps = (((p[0] + p[1]) + (p[2] + p[3])) + ((p[4] + p[5]) + (p[6] + p[7])))
           + (((p[8] + p[9]) + (p[10] + p[11])) + ((p[12] + p[13]) + (p[14] + p[15])));
        lsum = fmaf(lsum, alpha, ps);
#pragma unroll
        for (int r = 0; r < 16; ++r) { O0[r] *= alpha; O1[r] *= alpha; }

        unsigned pk[8];
#pragma unroll
        for (int hh = 0; hh < 8; ++hh) {
            auto prr = __builtin_amdgcn_cvt_pkrtz(p[2 * hh], p[2 * hh + 1]);
            unsigned pu; __builtin_memcpy(&pu, &prr, 4);
            pk[hh] = pu;
        }
#pragma unroll
        for (int s = 0; s < 2; ++s) {       // C-frag -> B-frag(P^T): lane^32 swap
            unsigned send0 = lh ? pk[4 * s + 0] : pk[4 * s + 2];
            unsigned send1 = lh ? pk[4 * s + 1] : pk[4 * s + 3];
            unsigned r0 = (unsigned)__shfl_xor((int)send0, 32);
            unsigned r1 = (unsigned)__shfl_xor((int)send1, 32);
            H8U4 pb;
            pb.u[0] = lh ? r0 : pk[4 * s + 0];
            pb.u[1] = lh ? r1 : pk[4 * s + 1];
            pb.u[2] = lh ? pk[4 * s + 2] : r0;
            pb.u[3] = lh ? pk[4 * s + 3] : r1;
            O0 = __builtin_amdgcn_mfma_f32_32x32x16_f16(vf[s], pb.v, O0, 0, 0, 0);
            O1 = __builtin_amdgcn_mfma_f32_32x32x16_f16(vf[2 + s], pb.v, O1, 0, 0, 0);
        }
    };

    auto compPair = [&](int jj, const h8 (&kf)[4]) {
        float4 hr[4];
#pragma unroll
        for (int g = 0; g < 4; ++g) hr[g] = hk4[jj * 8 + g * 2 + lh];
        h8 vf[4];
        const _Float16* vp = Vsb + (size_t)jj * 2048 + klq;
#pragma unroll
        for (int oc = 0; oc < 4; ++oc)
            vf[oc] = *(const h8*)(vp + (oc >> 1) * 1024 + (oc & 1) * 512);
        compQ(jj, kf, vf, hr, qf2, O0b, O1b, m2, l2, qt2);
        if (jj < T1)   // wave-uniform; two independent chains when taken
            compQ(jj, kf, vf, hr, qf1, O0a, O1a, m1, l1, qt1);
    };

    // rotated 2-deep K pipeline (no dynamic reg indexing); j0<j1 always
    h8 kfA[4], kfB[4];
    loadK(j0, kfA);
    int jj = j0;
    while (true) {
        if (jj + 1 < j1) loadK(jj + 1, kfB);
        compPair(jj, kfA);
        if (++jj >= j1) break;
        if (jj + 1 < j1) loadK(jj + 1, kfA);
        compPair(jj, kfB);
        if (++jj >= j1) break;
    }

    // merge: wave1 publishes both (m,l,O) states; wave0 flash-combines + stores
    if (wv) {
#pragma unroll
        for (int r = 0; r < 16; ++r) {
            sm[0][lane][r] = O0a[r]; sm[0][lane][16 + r] = O1a[r];
            sm[1][lane][r] = O0b[r]; sm[1][lane][16 + r] = O1b[r];
        }
        sm[0][lane][32] = l1 + __shfl_xor(l1, 32);
        sm[0][lane][33] = m1;
        sm[1][lane][32] = l2 + __shfl_xor(l2, 32);
        sm[1][lane][33] = m2;
    }
    __syncthreads();
    if (!wv) {
        auto mergeStore = [&](int si, const f32x16& O0, const f32x16& O1,
                              float mrun, float lsum, int qt) {
            float l0 = lsum + __shfl_xor(lsum, 32);
            float lo = sm[si][lane][32];
            float mo = sm[si][lane][33];
            float m = fmaxf(mrun, mo);
            float a0 = __builtin_amdgcn_exp2f(mrun - m);
            float a1 = __builtin_amdgcn_exp2f(mo - m);   // empty: -inf -> 0
            float lt = l0 * a0 + lo * a1;
            float inv = 1.f / lt;
            float s0 = a0 * inv, s1 = a1 * inv;
            size_t ro = fbase + (size_t)(qt * 32 + ln) * DD;
#pragma unroll
            for (int g = 0; g < 4; ++g) {
                float4 o0 = make_float4(
                    O0[4 * g + 0] * s0 + sm[si][lane][4 * g + 0] * s1,
                    O0[4 * g + 1] * s0 + sm[si][lane][4 * g + 1] * s1,
                    O0[4 * g + 2] * s0 + sm[si][lane][4 * g + 2] * s1,
                    O0[4 * g + 3] * s0 + sm[si][lane][4 * g + 3] * s1);
                *(float4*)&out[ro + 8 * g + 4 * lh] = o0;
                float4 o1 = make_float4(
                    O1[4 * g + 0] * s0 + sm[si][lane][16 + 4 * g + 0] * s1,
                    O1[4 * g + 1] * s0 + sm[si][lane][16 + 4 * g + 1] * s1,
                    O1[4 * g + 2] * s0 + sm[si][lane][16 + 4 * g + 2] * s1,
                    O1[4 * g + 3] * s0 + sm[si][lane][16 + 4 * g + 3] * s1);
                *(float4*)&out[ro + 32 + 8 * g + 4 * lh] = o1;
            }
        };
        mergeStore(0, O0a, O1a, m1, l1, qt1);
        mergeStore(1, O0b, O1b, m2, l2, qt2);
    }
}

extern "C" void kernel_launch(void* const* d_in, const int* in_sizes, int n_in,
                              void* d_out, int out_size, void* d_ws, size_t ws_size,
                              hipStream_t stream) {
    (void)in_sizes; (void)n_in; (void)out_size; (void)ws_size;
    const float* q = (const float*)d_in[0];
    const float* k = (const float*)d_in[1];
    const float* v = (const float*)d_in[2];
    float* out = (float*)d_out;

    // ws: [hk 256KB][Ks 8MB f16][Vs 8MB f16]
    float* hk = (float*)d_ws;
    _Float16* Ks = (_Float16*)((char*)d_ws + 262144);
    _Float16* Vs = (_Float16*)((char*)d_ws + 262144 + 8388608);

    prep<<<dim3(64, 32), 64, 0, stream>>>(k, v, Ks, Vs, hk);
    rbf_attn<<<dim3(32, 32), 128, 0, stream>>>(q, Ks, Vs, hk, out);
}

// Round 9
// 129.416 us; speedup vs baseline: 1.2678x; 1.0012x over previous
//
#include <hip/hip_runtime.h>

#define NN 2048
#define DD 64
#define C1 0.36067376f  // 2/sqrt(D) * log2(e)
#define C1H 0.18033688f // C1/2

typedef _Float16 h8 __attribute__((ext_vector_type(8)));
typedef _Float16 h4 __attribute__((ext_vector_type(4)));
typedef float f32x16 __attribute__((ext_vector_type(16)));

union H8U4 { h8 v; unsigned u[4]; };

// v_permlane32_swap_b32 vdst, vsrc semantics (gfx950, R8 post-mortem verified):
//   new_vdst = {vdst[0:31] | vsrc[0:31]}   (upper half of vdst <- lower of vsrc)
//   new_vsrc = {vdst[32:63] | vsrc[32:63]} (lower half of vsrc <- upper of vdst)
// Symmetric both-args-same helpers are correct under either convention.
static __device__ inline float ph_max(float v) {
    unsigned u; __builtin_memcpy(&u, &v, 4);
    auto rr = __builtin_amdgcn_permlane32_swap(u, u, false, false);
    unsigned r0 = rr[0], r1 = rr[1];
    float a, b; __builtin_memcpy(&a, &r0, 4); __builtin_memcpy(&b, &r1, 4);
    return fmaxf(a, b);
}
static __device__ inline float ph_sum(float v) {
    unsigned u; __builtin_memcpy(&u, &v, 4);
    auto rr = __builtin_amdgcn_permlane32_swap(u, u, false, false);
    unsigned r0 = rr[0], r1 = rr[1];
    float a, b; __builtin_memcpy(&a, &r0, 4); __builtin_memcpy(&b, &r1, 4);
    return a + b;
}

// ---- prep: frag-major swizzles so the main loop is pure coalesced loads ----
// Ks[bh][jj][c][lh][ln]{8}  = K[32jj+ln][16c+8lh+0..7]          (A-frag order)
// Vs[bh][jj][o][c][lh][ln]{8}= V[32jj+16c+8lh+j][32o+ln]        (V^T A-frag order)
// hk[bh][n] = C1H*||k_n||^2
__global__ __launch_bounds__(64) void prep(const float* __restrict__ k,
                                           const float* __restrict__ v,
                                           _Float16* __restrict__ Ks,
                                           _Float16* __restrict__ Vs,
                                           float* __restrict__ hk) {
    __shared__ _Float16 T[32][72];
    const int jj = blockIdx.x, bh = blockIdx.y, lane = threadIdx.x;
    const int ln = lane & 31, lh = lane >> 5;
    const size_t ibase = (size_t)bh * NN * DD + (size_t)jj * 32 * DD;

    { // K frags + row sumsq (lh halves cover complementary d-ranges)
        const float* kr = k + ibase + (size_t)ln * DD;
        float s = 0.f;
#pragma unroll
        for (int c = 0; c < 4; ++c) {
            float4 a = *(const float4*)&kr[16 * c + 8 * lh];
            float4 b = *(const float4*)&kr[16 * c + 8 * lh + 4];
            h8 o = {(_Float16)a.x, (_Float16)a.y, (_Float16)a.z, (_Float16)a.w,
                    (_Float16)b.x, (_Float16)b.y, (_Float16)b.z, (_Float16)b.w};
            *(h8*)&Ks[((size_t)bh * 16384 + jj * 256 + c * 64 + lh * 32 + ln) * 8] = o;
            s += a.x*a.x + a.y*a.y + a.z*a.z + a.w*a.w
               + b.x*b.x + b.y*b.y + b.z*b.z + b.w*b.w;
        }
        s += __shfl_xor(s, 32);
        if (lh == 0) hk[bh * NN + jj * 32 + ln] = s * C1H;
    }

    // V tile -> LDS f16 -> transposed frag-major store
#pragma unroll
    for (int t = 0; t < 8; ++t) {
        int f = lane + 64 * t;            // 512 float4 groups = 32 rows x 16
        int row = f >> 4, c4 = (f & 15) * 4;
        float4 a = *(const float4*)&v[ibase + (size_t)row * DD + c4];
        h4 hv = {(_Float16)a.x, (_Float16)a.y, (_Float16)a.z, (_Float16)a.w};
        *(h4*)&T[row][c4] = hv;
    }
    __syncthreads();
#pragma unroll
    for (int oc = 0; oc < 4; ++oc) {
        int o = oc >> 1, c = oc & 1;
        h8 r;
#pragma unroll
        for (int jx = 0; jx < 8; ++jx) r[jx] = T[16 * c + 8 * lh + jx][32 * o + ln];
        *(h8*)&Vs[((size_t)bh * 16384 + jj * 256 + o * 128 + c * 64 + lh * 32 + ln) * 8] = r;
    }
}

// ---- main: flash RBF, paired complementary q-tiles + key-split-2 ----
// Block = 2 waves on the q-tile PAIR (qt1=p, qt2=63-p): T1+T2 = 65 tile-units,
// constant -> 1024 uniform blocks, one generation. Chain-shortening (R8/R9):
// permlane32_swap (VALU) replaces all ds_bpermute lane^32 hops; O/lsum rescale
// only when a new running max appears (wave-uniform branch, alpha==1 otherwise).
// REGISTER CLASS: ~230 unified regs -> 2 waves/SIMD (R3/R5: forcing more
// spills to scratch; sentinel = WRITE_SIZE 16.4 MB).
__global__ __launch_bounds__(128, 2) void rbf_attn(
    const float* __restrict__ q, const _Float16* __restrict__ Ks,
    const _Float16* __restrict__ Vs, const float* __restrict__ hk,
    float* __restrict__ out)
{
    __shared__ float sm[2][64][34];      // wave1 publish: per q-tile O + l + m
    const int tid = threadIdx.x;
    const int bh = blockIdx.x;
    const int pr = blockIdx.y;           // pair index 0..31
    const int qt1 = pr, qt2 = 63 - pr;
    const int wv = tid >> 6, lane = tid & 63;
    const int ln = lane & 31, lh = lane >> 5;
    const size_t fbase = (size_t)bh * NN * DD;

    // Q B-frags for BOTH q-tiles straight from global f32
    h8 qf1[4], qf2[4];
    {
        const float* qr1 = q + fbase + (size_t)(qt1 * 32 + ln) * DD;
        const float* qr2 = q + fbase + (size_t)(qt2 * 32 + ln) * DD;
#pragma unroll
        for (int c = 0; c < 4; ++c) {
            float4 a = *(const float4*)&qr1[16 * c + 8 * lh];
            float4 b = *(const float4*)&qr1[16 * c + 8 * lh + 4];
            qf1[c] = h8{(_Float16)a.x, (_Float16)a.y, (_Float16)a.z, (_Float16)a.w,
                        (_Float16)b.x, (_Float16)b.y, (_Float16)b.z, (_Float16)b.w};
            float4 e = *(const float4*)&qr2[16 * c + 8 * lh];
            float4 f = *(const float4*)&qr2[16 * c + 8 * lh + 4];
            qf2[c] = h8{(_Float16)e.x, (_Float16)e.y, (_Float16)e.z, (_Float16)e.w,
                        (_Float16)f.x, (_Float16)f.y, (_Float16)f.z, (_Float16)f.w};
        }
    }

    const _Float16* Ksb = Ks + (size_t)bh * 131072;
    const _Float16* Vsb = Vs + (size_t)bh * 131072;
    const float4* hk4 = (const float4*)(hk + bh * NN);
    const int klq = (lh * 32 + ln) * 8;  // element offset of this lane's frag

    f32x16 O0a, O1a, O0b, O1b;
#pragma unroll
    for (int r = 0; r < 16; ++r) { O0a[r] = 0.f; O1a[r] = 0.f; O0b[r] = 0.f; O1b[r] = 0.f; }
    float l1 = 0.f, m1 = -INFINITY;      // qt1 online-softmax state
    float l2 = 0.f, m2 = -INFINITY;      // qt2 state

    const int T1 = qt1 + 1, T2 = qt2 + 1;
    const int h2 = (T2 + 1) >> 1;        // wave0: [0,h2), wave1: [h2,T2)
    const int j0 = wv ? h2 : 0;
    const int j1 = wv ? T2 : h2;

    auto loadK = [&](int jj, h8 (&kf)[4]) {
        const _Float16* kp = Ksb + (size_t)jj * 2048 + klq;
#pragma unroll
        for (int c = 0; c < 4; ++c) kf[c] = *(const h8*)(kp + c * 512);
    };

    auto compQ = [&](int jj, const h8 (&kf)[4], const h8 (&vf)[4],
                     const float4 (&hr)[4], const h8 (&qf)[4],
                     f32x16& O0, f32x16& O1, float& mrun, float& lsum, int dqt) {
        f32x16 S;
#pragma unroll
        for (int r = 0; r < 16; ++r) S[r] = 0.f;
#pragma unroll
        for (int c = 0; c < 4; ++c)
            S = __builtin_amdgcn_mfma_f32_32x32x16_f16(kf[c], qf[c], S, 0, 0, 0);

        const bool diag = (jj == dqt);
        float x[16];
#pragma unroll
        for (int r = 0; r < 16; ++r) {
            const float* hf = (const float*)&hr[r >> 2];
            float xv = fmaf(S[r], C1, -hf[r & 3]);
            if (diag) {
                int keyloc = (r & 3) + 8 * (r >> 2) + 4 * lh;
                if (keyloc > ln) xv = -INFINITY;
            }
            x[r] = xv;
        }
        // fmax tree + VALU half-combine (no DS hop)
        float a0 = fmaxf(x[0], x[1]),  a1 = fmaxf(x[2], x[3]);
        float a2 = fmaxf(x[4], x[5]),  a3 = fmaxf(x[6], x[7]);
        float a4 = fmaxf(x[8], x[9]),  a5 = fmaxf(x[10], x[11]);
        float a6 = fmaxf(x[12], x[13]), a7 = fmaxf(x[14], x[15]);
        float mt = fmaxf(fmaxf(fmaxf(a0, a1), fmaxf(a2, a3)),
                         fmaxf(fmaxf(a4, a5), fmaxf(a6, a7)));
        mt = ph_max(mt);
        float mnew = fmaxf(mrun, mt);
        float p[16], ps;
#pragma unroll
        for (int r = 0; r < 16; ++r) p[r] = __builtin_amdgcn_exp2f(x[r] - mnew);
        ps = (((p[0] + p[1]) + (p[2] + p[3])) + ((p[4] + p[5]) + (p[6] + p[7])))
           + (((p[8] + p[9]) + (p[10] + p[11])) + ((p[12] + p[13]) + (p[14] + p[15])));
        if (__any(mt > mrun)) {          // new record somewhere: rescale (rare)
            float alpha = __builtin_amdgcn_exp2f(mrun - mnew);
            lsum = fmaf(lsum, alpha, ps);
#pragma unroll
            for (int r = 0; r < 16; ++r) { O0[r] *= alpha; O1[r] *= alpha; }
        } else {                         // alpha == 1 for every lane
            lsum += ps;
        }
        mrun = mnew;

        unsigned pk[8];
#pragma unroll
        for (int hh = 0; hh < 8; ++hh) {
            auto prr = __builtin_amdgcn_cvt_pkrtz(p[2 * hh], p[2 * hh + 1]);
            unsigned pu; __builtin_memcpy(&pu, &prr, 4);
            pk[hh] = pu;
        }
#pragma unroll
        for (int s = 0; s < 2; ++s) {
            // C-frag -> B-frag(P^T). Desired:
            //   pb.u[0] = {own pk0 | partner pk2},  pb.u[2] = {partner pk0 | own pk2}
            //   pb.u[1] = {own pk1 | partner pk3},  pb.u[3] = {partner pk1 | own pk3}
            // swap(pk0, pk2) -> r[0] = {pk0_lo | pk2_lo-of-partner...} per the
            // upper(vdst)<->lower(vsrc) semantics: r[0]=pb.u[0], r[1]=pb.u[2].
            auto r02 = __builtin_amdgcn_permlane32_swap(pk[4 * s + 0], pk[4 * s + 2],
                                                        false, false);
            auto r13 = __builtin_amdgcn_permlane32_swap(pk[4 * s + 1], pk[4 * s + 3],
                                                        false, false);
            H8U4 pb;
            pb.u[0] = r02[0];
            pb.u[1] = r13[0];
            pb.u[2] = r02[1];
            pb.u[3] = r13[1];
            O0 = __builtin_amdgcn_mfma_f32_32x32x16_f16(vf[s], pb.v, O0, 0, 0, 0);
            O1 = __builtin_amdgcn_mfma_f32_32x32x16_f16(vf[2 + s], pb.v, O1, 0, 0, 0);
        }
    };

    auto compPair = [&](int jj, const h8 (&kf)[4]) {
        float4 hr[4];
#pragma unroll
        for (int g = 0; g < 4; ++g) hr[g] = hk4[jj * 8 + g * 2 + lh];
        h8 vf[4];
        const _Float16* vp = Vsb + (size_t)jj * 2048 + klq;
#pragma unroll
        for (int oc = 0; oc < 4; ++oc)
            vf[oc] = *(const h8*)(vp + (oc >> 1) * 1024 + (oc & 1) * 512);
        compQ(jj, kf, vf, hr, qf2, O0b, O1b, m2, l2, qt2);
        if (jj < T1)   // wave-uniform; two independent chains when taken
            compQ(jj, kf, vf, hr, qf1, O0a, O1a, m1, l1, qt1);
    };

    // rotated 2-deep K pipeline (no dynamic reg indexing); j0<j1 always
    h8 kfA[4], kfB[4];
    loadK(j0, kfA);
    int jj = j0;
    while (true) {
        if (jj + 1 < j1) loadK(jj + 1, kfB);
        compPair(jj, kfA);
        if (++jj >= j1) break;
        if (jj + 1 < j1) loadK(jj + 1, kfA);
        compPair(jj, kfB);
        if (++jj >= j1) break;
    }

    // merge: wave1 publishes both (m,l,O) states; wave0 flash-combines + stores
    if (wv) {
#pragma unroll
        for (int r = 0; r < 16; ++r) {
            sm[0][lane][r] = O0a[r]; sm[0][lane][16 + r] = O1a[r];
            sm[1][lane][r] = O0b[r]; sm[1][lane][16 + r] = O1b[r];
        }
        sm[0][lane][32] = ph_sum(l1);
        sm[0][lane][33] = m1;
        sm[1][lane][32] = ph_sum(l2);
        sm[1][lane][33] = m2;
    }
    __syncthreads();
    if (!wv) {
        auto mergeStore = [&](int si, const f32x16& O0, const f32x16& O1,
                              float mrun, float lsum, int qt) {
            float l0 = ph_sum(lsum);
            float lo = sm[si][lane][32];
            float mo = sm[si][lane][33];
            float m = fmaxf(mrun, mo);
            float a0 = __builtin_amdgcn_exp2f(mrun - m);
            float a1 = __builtin_amdgcn_exp2f(mo - m);   // empty: -inf -> 0
            float lt = l0 * a0 + lo * a1;
            float inv = 1.f / lt;
            float s0 = a0 * inv, s1 = a1 * inv;
            size_t ro = fbase + (size_t)(qt * 32 + ln) * DD;
#pragma unroll
            for (int g = 0; g < 4; ++g) {
                float4 o0 = make_float4(
                    O0[4 * g + 0] * s0 + sm[si][lane][4 * g + 0] * s1,
                    O0[4 * g + 1] * s0 + sm[si][lane][4 * g + 1] * s1,
                    O0[4 * g + 2] * s0 + sm[si][lane][4 * g + 2] * s1,
                    O0[4 * g + 3] * s0 + sm[si][lane][4 * g + 3] * s1);
                *(float4*)&out[ro + 8 * g + 4 * lh] = o0;
                float4 o1 = make_float4(
                    O1[4 * g + 0] * s0 + sm[si][lane][16 + 4 * g + 0] * s1,
                    O1[4 * g + 1] * s0 + sm[si][lane][16 + 4 * g + 1] * s1,
                    O1[4 * g + 2] * s0 + sm[si][lane][16 + 4 * g + 2] * s1,
                    O1[4 * g + 3] * s0 + sm[si][lane][16 + 4 * g + 3] * s1);
                *(float4*)&out[ro + 32 + 8 * g + 4 * lh] = o1;
            }
        };
        mergeStore(0, O0a, O1a, m1, l1, qt1);
        mergeStore(1, O0b, O1b, m2, l2, qt2);
    }
}

extern "C" void kernel_launch(void* const* d_in, const int* in_sizes, int n_in,
                              void* d_out, int out_size, void* d_ws, size_t ws_size,
                              hipStream_t stream) {
    (void)in_sizes; (void)n_in; (void)out_size; (void)ws_size;
    const float* q = (const float*)d_in[0];
    const float* k = (const float*)d_in[1];
    const float* v = (const float*)d_in[2];
    float* out = (float*)d_out;

    // ws: [hk 256KB][Ks 8MB f16][Vs 8MB f16]
    float* hk = (float*)d_ws;
    _Float16* Ks = (_Float16*)((char*)d_ws + 262144);
    _Float16* Vs = (_Float16*)((char*)d_ws + 262144 + 8388608);

    prep<<<dim3(64, 32), 64, 0, stream>>>(k, v, Ks, Vs, hk);
    rbf_attn<<<dim3(32, 32), 128, 0, stream>>>(q, Ks, Vs, hk, out);
}

// Round 10
// 128.935 us; speedup vs baseline: 1.2725x; 1.0037x over previous
//
#include <hip/hip_runtime.h>

#define NN 2048
#define DD 64
#define C1 0.36067376f  // 2/sqrt(D) * log2(e)
#define C1H 0.18033688f // C1/2

typedef _Float16 h8 __attribute__((ext_vector_type(8)));
typedef _Float16 h4 __attribute__((ext_vector_type(4)));
typedef float f32x16 __attribute__((ext_vector_type(16)));

union H8U4 { h8 v; unsigned u[4]; };

// v_permlane32_swap_b32 semantics (gfx950, verified on HW in R9):
//   swap(a,b): r[0] = {a[0:31] | b[0:31]};  r[1] = {a[32:63] | b[32:63]}
// (upper half of a exchanged with lower half of b). Symmetric helpers below
// are correct under either convention; pk-swap orientation verified R9.
static __device__ inline float ph_max(float v) {
    unsigned u; __builtin_memcpy(&u, &v, 4);
    auto rr = __builtin_amdgcn_permlane32_swap(u, u, false, false);
    unsigned r0 = rr[0], r1 = rr[1];
    float a, b; __builtin_memcpy(&a, &r0, 4); __builtin_memcpy(&b, &r1, 4);
    return fmaxf(a, b);
}
static __device__ inline float ph_sum(float v) {
    unsigned u; __builtin_memcpy(&u, &v, 4);
    auto rr = __builtin_amdgcn_permlane32_swap(u, u, false, false);
    unsigned r0 = rr[0], r1 = rr[1];
    float a, b; __builtin_memcpy(&a, &r0, 4); __builtin_memcpy(&b, &r1, 4);
    return a + b;
}

// ---- prep: frag-major swizzles so the main loop is pure coalesced loads ----
// Ks[bh][jj][c][lh][ln]{8}  = K[32jj+ln][16c+8lh+0..7]          (A-frag order)
// Vs[bh][jj][o][c][lh][ln]{8}= V[32jj+16c+8lh+j][32o+ln]        (V^T A-frag order)
// hk[bh][n] = C1H*||k_n||^2
__global__ __launch_bounds__(64) void prep(const float* __restrict__ k,
                                           const float* __restrict__ v,
                                           _Float16* __restrict__ Ks,
                                           _Float16* __restrict__ Vs,
                                           float* __restrict__ hk) {
    __shared__ _Float16 T[32][72];
    const int jj = blockIdx.x, bh = blockIdx.y, lane = threadIdx.x;
    const int ln = lane & 31, lh = lane >> 5;
    const size_t ibase = (size_t)bh * NN * DD + (size_t)jj * 32 * DD;

    { // K frags + row sumsq (lh halves cover complementary d-ranges)
        const float* kr = k + ibase + (size_t)ln * DD;
        float s = 0.f;
#pragma unroll
        for (int c = 0; c < 4; ++c) {
            float4 a = *(const float4*)&kr[16 * c + 8 * lh];
            float4 b = *(const float4*)&kr[16 * c + 8 * lh + 4];
            h8 o = {(_Float16)a.x, (_Float16)a.y, (_Float16)a.z, (_Float16)a.w,
                    (_Float16)b.x, (_Float16)b.y, (_Float16)b.z, (_Float16)b.w};
            *(h8*)&Ks[((size_t)bh * 16384 + jj * 256 + c * 64 + lh * 32 + ln) * 8] = o;
            s += a.x*a.x + a.y*a.y + a.z*a.z + a.w*a.w
               + b.x*b.x + b.y*b.y + b.z*b.z + b.w*b.w;
        }
        s += __shfl_xor(s, 32);
        if (lh == 0) hk[bh * NN + jj * 32 + ln] = s * C1H;
    }

    // V tile -> LDS f16 -> transposed frag-major store
#pragma unroll
    for (int t = 0; t < 8; ++t) {
        int f = lane + 64 * t;            // 512 float4 groups = 32 rows x 16
        int row = f >> 4, c4 = (f & 15) * 4;
        float4 a = *(const float4*)&v[ibase + (size_t)row * DD + c4];
        h4 hv = {(_Float16)a.x, (_Float16)a.y, (_Float16)a.z, (_Float16)a.w};
        *(h4*)&T[row][c4] = hv;
    }
    __syncthreads();
#pragma unroll
    for (int oc = 0; oc < 4; ++oc) {
        int o = oc >> 1, c = oc & 1;
        h8 r;
#pragma unroll
        for (int jx = 0; jx < 8; ++jx) r[jx] = T[16 * c + 8 * lh + jx][32 * o + ln];
        *(h8*)&Vs[((size_t)bh * 16384 + jj * 256 + o * 128 + c * 64 + lh * 32 + ln) * 8] = r;
    }
}

// ---- main: flash RBF, key-split-2, QK/softmax SOFTWARE PIPELINE ----
// Block = 2 waves on one 32-row q-tile; wave0 keys [0,ceil(T/2)), wave1 rest.
// Per phase: issue NEXT tile's 4 QK MFMAs (independent S buffer), prefetch
// K(+2), then softmax+PV of CURRENT S — one straight-line BB so the scheduler
// interleaves softmax VALU between the dependent MFMAs (hides MFMA latency).
// Unconditional rescale (R9's __any branch regressed: BB split kills sched).
// REGISTER CLASS: ~175 unified -> 2 waves/SIMD. R3/R5: forcing 3-4 waves
// spills to scratch. Sentinels: WRITE_SIZE 16.4 MB, VGPR ~120.
__global__ __launch_bounds__(128, 2) void rbf_attn(
    const float* __restrict__ q, const _Float16* __restrict__ Ks,
    const _Float16* __restrict__ Vs, const float* __restrict__ hk,
    float* __restrict__ out)
{
    __shared__ float sm[64][34];         // wave1: O (32 f32/lane) + l + m
    const int tid = threadIdx.x;
    const int bh = blockIdx.x;
    const int qt = 63 - (int)blockIdx.y; // q-tile (32 rows); LPT: heavy first
    const int wv = tid >> 6, lane = tid & 63;
    const int ln = lane & 31, lh = lane >> 5;
    const int qrow = qt * 32 + ln;
    const size_t fbase = (size_t)bh * NN * DD;

    // Q B-frags straight from global f32 (per-lane 16B-contiguous, L2-hot)
    h8 qf[4];
    {
        const float* qr = q + fbase + (size_t)qrow * DD;
#pragma unroll
        for (int c = 0; c < 4; ++c) {
            float4 a = *(const float4*)&qr[16 * c + 8 * lh];
            float4 b = *(const float4*)&qr[16 * c + 8 * lh + 4];
            qf[c] = h8{(_Float16)a.x, (_Float16)a.y, (_Float16)a.z, (_Float16)a.w,
                       (_Float16)b.x, (_Float16)b.y, (_Float16)b.z, (_Float16)b.w};
        }
    }

    const _Float16* Ksb = Ks + (size_t)bh * 131072;
    const _Float16* Vsb = Vs + (size_t)bh * 131072;
    const float4* hk4 = (const float4*)(hk + bh * NN);
    const int klq = (lh * 32 + ln) * 8;  // element offset of this lane's frag

    f32x16 O0, O1;
#pragma unroll
    for (int r = 0; r < 16; ++r) { O0[r] = 0.f; O1[r] = 0.f; }
    float lsum = 0.f, mrun = -INFINITY;

    const int T = qt + 1;                // key tiles for this q-tile
    const int half = (T + 1) >> 1;       // wave0 gets ceil (wave1 pays diag mask)
    const int j0 = wv ? half : 0;
    const int j1 = wv ? T : half;

    auto loadK = [&](int jj, h8 (&kf)[4]) {
        const _Float16* kp = Ksb + (size_t)jj * 2048 + klq;
#pragma unroll
        for (int c = 0; c < 4; ++c) kf[c] = *(const h8*)(kp + c * 512);
    };

    auto qk = [&](const h8 (&kf)[4]) {
        f32x16 S;
#pragma unroll
        for (int r = 0; r < 16; ++r) S[r] = 0.f;
#pragma unroll
        for (int c = 0; c < 4; ++c)
            S = __builtin_amdgcn_mfma_f32_32x32x16_f16(kf[c], qf[c], S, 0, 0, 0);
        return S;
    };

    // softmax + PV for tile jj, consuming precomputed S (R7 math, R9 permlane)
    auto smpv = [&](int jj, const f32x16& S) {
        float4 hr[4];
#pragma unroll
        for (int g = 0; g < 4; ++g) hr[g] = hk4[jj * 8 + g * 2 + lh];
        h8 vf[4];
        const _Float16* vp = Vsb + (size_t)jj * 2048 + klq;
#pragma unroll
        for (int oc = 0; oc < 4; ++oc)
            vf[oc] = *(const h8*)(vp + (oc >> 1) * 1024 + (oc & 1) * 512);

        const bool diag = (jj == qt);
        float x[16];
#pragma unroll
        for (int r = 0; r < 16; ++r) {
            const float* hf = (const float*)&hr[r >> 2];
            float xv = fmaf(S[r], C1, -hf[r & 3]);
            if (diag) {
                int keyloc = (r & 3) + 8 * (r >> 2) + 4 * lh;
                if (keyloc > ln) xv = -INFINITY;
            }
            x[r] = xv;
        }
        float a0 = fmaxf(x[0], x[1]),  a1 = fmaxf(x[2], x[3]);
        float a2 = fmaxf(x[4], x[5]),  a3 = fmaxf(x[6], x[7]);
        float a4 = fmaxf(x[8], x[9]),  a5 = fmaxf(x[10], x[11]);
        float a6 = fmaxf(x[12], x[13]), a7 = fmaxf(x[14], x[15]);
        float mt = fmaxf(fmaxf(fmaxf(a0, a1), fmaxf(a2, a3)),
                         fmaxf(fmaxf(a4, a5), fmaxf(a6, a7)));
        mt = ph_max(mt);
        float mnew = fmaxf(mrun, mt);
        float alpha = __builtin_amdgcn_exp2f(mrun - mnew);
        mrun = mnew;
        float p[16], ps;
#pragma unroll
        for (int r = 0; r < 16; ++r) p[r] = __builtin_amdgcn_exp2f(x[r] - mnew);
        ps = (((p[0] + p[1]) + (p[2] + p[3])) + ((p[4] + p[5]) + (p[6] + p[7])))
           + (((p[8] + p[9]) + (p[10] + p[11])) + ((p[12] + p[13]) + (p[14] + p[15])));
        lsum = fmaf(lsum, alpha, ps);
#pragma unroll
        for (int r = 0; r < 16; ++r) { O0[r] *= alpha; O1[r] *= alpha; }

        unsigned pk[8];
#pragma unroll
        for (int hh = 0; hh < 8; ++hh) {
            auto prr = __builtin_amdgcn_cvt_pkrtz(p[2 * hh], p[2 * hh + 1]);
            unsigned pu; __builtin_memcpy(&pu, &prr, 4);
            pk[hh] = pu;
        }
#pragma unroll
        for (int s = 0; s < 2; ++s) {    // C-frag -> B-frag(P^T), R9-verified
            auto r02 = __builtin_amdgcn_permlane32_swap(pk[4 * s + 0], pk[4 * s + 2],
                                                        false, false);
            auto r13 = __builtin_amdgcn_permlane32_swap(pk[4 * s + 1], pk[4 * s + 3],
                                                        false, false);
            H8U4 pb;
            pb.u[0] = r02[0];
            pb.u[1] = r13[0];
            pb.u[2] = r02[1];
            pb.u[3] = r13[1];
            O0 = __builtin_amdgcn_mfma_f32_32x32x16_f16(vf[s], pb.v, O0, 0, 0, 0);
            O1 = __builtin_amdgcn_mfma_f32_32x32x16_f16(vf[2 + s], pb.v, O1, 0, 0, 0);
        }
    };

    // pipelined rotated loop: S double-buffer, K 2-deep prefetch (clamped,
    // garbage loads at the tail are in-workspace and never consumed)
    if (j0 < j1) {
        h8 kfA[4], kfB[4];
        loadK(j0, kfA);
        int jp = (j0 + 1 < j1) ? j0 + 1 : j1 - 1;
        loadK(jp, kfB);
        f32x16 Sa = qk(kfA);
        f32x16 Sb;
        int jj = j0;
        while (true) {
            // phase A: S for jj ready in Sa; kfB holds jj+1 (or clamp)
            Sb = qk(kfB);                                  // next tile's QK
            { int jn = (jj + 2 < j1) ? jj + 2 : j1 - 1; loadK(jn, kfA); }
            smpv(jj, Sa);                                  // interleaves w/ QK
            if (++jj >= j1) break;
            // phase B: roles swapped
            Sa = qk(kfA);
            { int jn = (jj + 2 < j1) ? jj + 2 : j1 - 1; loadK(jn, kfB); }
            smpv(jj, Sb);
            if (++jj >= j1) break;
        }
    }

    // merge: wave1 publishes (m,l,O); wave0 flash-combines, normalizes, stores
    if (wv) {
#pragma unroll
        for (int r = 0; r < 16; ++r) { sm[lane][r] = O0[r]; sm[lane][16 + r] = O1[r]; }
        sm[lane][32] = ph_sum(lsum);
        sm[lane][33] = mrun;
    }
    __syncthreads();
    if (!wv) {
        float l0 = ph_sum(lsum);
        float l1 = sm[lane][32];
        float m1 = sm[lane][33];
        float m = fmaxf(mrun, m1);
        float a0 = __builtin_amdgcn_exp2f(mrun - m);
        float a1 = __builtin_amdgcn_exp2f(m1 - m);   // wave1 empty: m1=-inf -> 0
        float lt = l0 * a0 + l1 * a1;
        float inv = 1.f / lt;
        float s0 = a0 * inv, s1 = a1 * inv;
        size_t ro = fbase + (size_t)qrow * DD;
#pragma unroll
        for (int g = 0; g < 4; ++g) {
            float4 o0 = make_float4(O0[4 * g + 0] * s0 + sm[lane][4 * g + 0] * s1,
                                    O0[4 * g + 1] * s0 + sm[lane][4 * g + 1] * s1,
                                    O0[4 * g + 2] * s0 + sm[lane][4 * g + 2] * s1,
                                    O0[4 * g + 3] * s0 + sm[lane][4 * g + 3] * s1);
            *(float4*)&out[ro + 8 * g + 4 * lh] = o0;
            float4 o1 = make_float4(O1[4 * g + 0] * s0 + sm[lane][16 + 4 * g + 0] * s1,
                                    O1[4 * g + 1] * s0 + sm[lane][16 + 4 * g + 1] * s1,
                                    O1[4 * g + 2] * s0 + sm[lane][16 + 4 * g + 2] * s1,
                                    O1[4 * g + 3] * s0 + sm[lane][16 + 4 * g + 3] * s1);
            *(float4*)&out[ro + 32 + 8 * g + 4 * lh] = o1;
        }
    }
}

extern "C" void kernel_launch(void* const* d_in, const int* in_sizes, int n_in,
                              void* d_out, int out_size, void* d_ws, size_t ws_size,
                              hipStream_t stream) {
    (void)in_sizes; (void)n_in; (void)out_size; (void)ws_size;
    const float* q = (const float*)d_in[0];
    const float* k = (const float*)d_in[1];
    const float* v = (const float*)d_in[2];
    float* out = (float*)d_out;

    // ws: [hk 256KB][Ks 8MB f16][Vs 8MB f16]
    float* hk = (float*)d_ws;
    _Float16* Ks = (_Float16*)((char*)d_ws + 262144);
    _Float16* Vs = (_Float16*)((char*)d_ws + 262144 + 8388608);

    prep<<<dim3(64, 32), 64, 0, stream>>>(k, v, Ks, Vs, hk);
    rbf_attn<<<dim3(32, 64), 128, 0, stream>>>(q, Ks, Vs, hk, out);
}